// Round 4
// baseline (323.949 us; speedup 1.0000x reference)
//
#include <hip/hip_runtime.h>
#include <cstdint>
#include <cstddef>

#define B_   4
#define S_   2048
#define D_   1024
#define H_   16
#define DH_  64

typedef __attribute__((ext_vector_type(8))) short short8;
typedef __attribute__((ext_vector_type(4))) float f32x4;

// fp32 -> bf16 (RNE)
static __device__ __forceinline__ unsigned short f2b(float f){
    unsigned int u = __float_as_uint(f);
    return (unsigned short)((u + 0x7FFFu + ((u >> 16) & 1u)) >> 16);
}

// ---------------------------------------------------------------------------
// prep 1: x fp32 -> bf16, flat copy. 8.4M elems, 8 per thread.
// ---------------------------------------------------------------------------
__global__ __launch_bounds__(256)
void cvt_x_kernel(const float* __restrict__ x, unsigned short* __restrict__ xb){
    size_t i0 = ((size_t)blockIdx.x * 256 + threadIdx.x) * 8;
    float4 a = *(const float4*)(x + i0);
    float4 b = *(const float4*)(x + i0 + 4);
    union { unsigned short u[8]; uint4 v; } r;
    r.u[0]=f2b(a.x); r.u[1]=f2b(a.y); r.u[2]=f2b(a.z); r.u[3]=f2b(a.w);
    r.u[4]=f2b(b.x); r.u[5]=f2b(b.y); r.u[6]=f2b(b.z); r.u[7]=f2b(b.w);
    *(uint4*)(xb + i0) = r.v;
}

// ---------------------------------------------------------------------------
// prep 2: W[q|k|v] fp32 [H][D][DH] -> wt bf16 [3][H][DH][D] (k-major for MFMA
// B-fragments: each lane needs 8 CONTIGUOUS k elements).
// ---------------------------------------------------------------------------
__global__ __launch_bounds__(256)
void cvt_w_kernel(const float* __restrict__ Wq, const float* __restrict__ Wk,
                  const float* __restrict__ Wv, unsigned short* __restrict__ wt){
    int id = blockIdx.x * 256 + threadIdx.x;   // 0 .. 786431 = 3*16*1024*16
    int e4 = (id & 15) * 4;
    int k  = (id >> 4) & 1023;
    int h  = (id >> 14) & 15;
    int t_ = id >> 18;                         // 0..2
    const float* W = (t_ == 0) ? Wq : ((t_ == 1) ? Wk : Wv);
    float4 w = *(const float4*)(W + (((size_t)h * D_ + k) * DH_ + e4));
    unsigned short* dst = wt + (((size_t)t_ * H_ + h) * DH_ + e4) * D_ + k;
    dst[0]            = f2b(w.x);
    dst[(size_t)D_]   = f2b(w.y);
    dst[(size_t)2*D_] = f2b(w.z);
    dst[(size_t)3*D_] = f2b(w.w);
}

// ---------------------------------------------------------------------------
// Kernel 1: QKV projection with bf16 MFMA (16x16x32).
// grid=(64,16): 128 rows of x, one head; N = 192 (q|k|v concatenated).
// 4 waves: wave w owns rows 32w..32w+31 (2 m-tiles), all 12 n-tiles.
// Frag layouts (guide-verified): A[row=l&15][k=(l>>4)*8+i];
// B[k=(l>>4)*8+i][col=l&15]; C/D[row=(l>>4)*4+r][col=l&15].
// Writes: qb (pre-scaled 1/8), kb as [bh][s][64] bf16; v TRANSPOSED to
// vt [bh][e][s] bf16 (PV B-operand needs k(=kv)-contiguous reads).
// ---------------------------------------------------------------------------
__global__ __launch_bounds__(256)
void qkv_proj_mfma(const unsigned short* __restrict__ xb,
                   const unsigned short* __restrict__ wtg,
                   const float* __restrict__ bq, const float* __restrict__ bk,
                   const float* __restrict__ bv,
                   unsigned short* __restrict__ qb,
                   unsigned short* __restrict__ kb,
                   unsigned short* __restrict__ vt)
{
    const int mb  = blockIdx.x;          // 0..63
    const int h   = blockIdx.y;          // 0..15
    const int t   = threadIdx.x;
    const int w   = t >> 6;
    const int l   = t & 63;
    const int l15 = l & 15;
    const int g   = l >> 4;

    __shared__ unsigned short xs[128][72];   // +8 pad: stride 144B -> 2-way (free)
    __shared__ unsigned short ws[192][72];
    __shared__ float bias_s[192];

    if (t < 192){
        int tensor = t >> 6, eloc = t & 63;
        const float* bp = (tensor == 0) ? bq : ((tensor == 1) ? bk : bv);
        bias_s[t] = bp[h * DH_ + eloc];
    }

    f32x4 acc[2][12];
#pragma unroll
    for (int mt = 0; mt < 2; ++mt)
#pragma unroll
        for (int nt = 0; nt < 12; ++nt) acc[mt][nt] = (f32x4){0.f,0.f,0.f,0.f};

    const int m0 = mb * 128;

    for (int k0 = 0; k0 < D_; k0 += 64){
        __syncthreads();                 // prev iter's LDS reads done
        // stage x tile: 128 rows x 64 bf16, 1024 16B-chunks
#pragma unroll
        for (int it = 0; it < 4; ++it){
            int c = t + it * 256;
            int row = c >> 3, off = (c & 7) * 8;
            *(short8*)&xs[row][off] =
                *(const short8*)(xb + (size_t)(m0 + row) * D_ + k0 + off);
        }
        // stage W tile: 192 rows (e') x 64 bf16 (k), 1536 chunks
#pragma unroll
        for (int it = 0; it < 6; ++it){
            int c = t + it * 256;
            int row = c >> 3, off = (c & 7) * 8;
            int tensor = row >> 6, eloc = row & 63;
            *(short8*)&ws[row][off] =
                *(const short8*)(wtg + (((size_t)tensor * H_ + h) * DH_ + eloc) * D_ + k0 + off);
        }
        __syncthreads();

#pragma unroll
        for (int ks = 0; ks < 2; ++ks){
            short8 a0 = *(const short8*)&xs[32*w + l15     ][32*ks + g*8];
            short8 a1 = *(const short8*)&xs[32*w + 16 + l15][32*ks + g*8];
#pragma unroll
            for (int nt = 0; nt < 12; ++nt){
                short8 bb = *(const short8*)&ws[16*nt + l15][32*ks + g*8];
                acc[0][nt] = __builtin_amdgcn_mfma_f32_16x16x32_bf16(a0, bb, acc[0][nt], 0,0,0);
                acc[1][nt] = __builtin_amdgcn_mfma_f32_16x16x32_bf16(a1, bb, acc[1][nt], 0,0,0);
            }
        }
    }

    // epilogue: bias add, dtype convert, scatter to q/k/vt
    const int b   = m0 >> 11;            // 2048 rows per batch
    const int bh  = b * H_ + h;
    const int sb  = (m0 & (S_ - 1)) + 32 * w;
#pragma unroll
    for (int mt = 0; mt < 2; ++mt){
        int s0 = sb + 16 * mt + 4 * g;   // 4 consecutive s at regs r=0..3
#pragma unroll
        for (int nt = 0; nt < 12; ++nt){
            float bias = bias_s[16 * nt + l15];
            if (nt < 4){                 // q, scaled by 1/sqrt(DH)
                int e = 16 * nt + l15;
                size_t base = ((size_t)bh * S_ + s0) * DH_ + e;
#pragma unroll
                for (int r = 0; r < 4; ++r)
                    qb[base + (size_t)r * DH_] = f2b((acc[mt][nt][r] + bias) * 0.125f);
            } else if (nt < 8){          // k
                int e = 16 * (nt - 4) + l15;
                size_t base = ((size_t)bh * S_ + s0) * DH_ + e;
#pragma unroll
                for (int r = 0; r < 4; ++r)
                    kb[base + (size_t)r * DH_] = f2b(acc[mt][nt][r] + bias);
            } else {                     // v -> vt[bh][e][s], 4 consecutive s = 8B store
                int e = 16 * (nt - 8) + l15;
                union { unsigned short u[4]; uint2 v; } pk;
#pragma unroll
                for (int r = 0; r < 4; ++r) pk.u[r] = f2b(acc[mt][nt][r] + bias);
                *(uint2*)(vt + ((size_t)bh * DH_ + e) * S_ + s0) = pk.v;
            }
        }
    }
}

// ---------------------------------------------------------------------------
// Kernel 2: flash attention, bf16 MFMA, swapped QK^T.
// grid=(32, 64): 64 q-rows per block (wave w owns 16), KV tiles of 64.
// S^T = K · Q^T  (A=K row-major k=e contiguous; B=Q^T from q registers)
//   -> lane holds S[q=l&15][kv=16mt+4g+r]: softmax = 16 local + shfl_xor 16,32.
// P -> per-wave LDS (bf16) -> A-frag of PV; V^T tile staged row-major from vt.
// O accum rows are q'=4g+r -> corr/l fetched via __shfl from lane 4g+r.
// ROUND-3 FIX: K/V staging wrote 8-elem chunks at 16-elem stride (half of
// each tile left as uninitialized LDS -> NaN). Now 512 chunks via 2 iters.
// ---------------------------------------------------------------------------
__global__ __launch_bounds__(256)
void attn_mfma(const unsigned short* __restrict__ qb,
               const unsigned short* __restrict__ kb,
               const unsigned short* __restrict__ vt,
               float* __restrict__ out)
{
    const int qt  = blockIdx.x;          // 0..31
    const int bh  = blockIdx.y;          // 0..63
    const int b   = bh >> 4, h = bh & 15;
    const int t   = threadIdx.x;
    const int w   = t >> 6;
    const int l   = t & 63;
    const int l15 = l & 15;
    const int g   = l >> 4;

    __shared__ unsigned short Kl [64][72];
    __shared__ unsigned short Vtl[64][72];
    __shared__ unsigned short Pl [4][16][72];

    const size_t bhb = (size_t)bh * S_ * DH_;

    // Q fragments in registers (q pre-scaled by 1/8 in proj)
    short8 qf[2];
    {
        const int qrow = qt * 64 + 16 * w + l15;
        const unsigned short* qp = qb + bhb + (size_t)qrow * DH_ + g * 8;
        qf[0] = *(const short8*)(qp);
        qf[1] = *(const short8*)(qp + 32);
    }

    f32x4 o[4];
#pragma unroll
    for (int nt = 0; nt < 4; ++nt) o[nt] = (f32x4){0.f,0.f,0.f,0.f};
    float m_r = -1e30f, l_r = 0.f;

    for (int kt = 0; kt < S_ / 64; ++kt){
        __syncthreads();                 // prev tile's LDS reads done
        // stage K (row-major [kv][e]) and V^T (row-major [e][kv]):
        // 64x64 bf16 = 512 16B-chunks each, 2 chunks/thread.
#pragma unroll
        for (int it = 0; it < 2; ++it){
            int c = t + it * 256;
            int row = c >> 3, off = (c & 7) * 8;
            *(short8*)&Kl[row][off] =
                *(const short8*)(kb + bhb + (size_t)(kt * 64 + row) * DH_ + off);
            *(short8*)&Vtl[row][off] =
                *(const short8*)(vt + bhb + (size_t)row * S_ + kt * 64 + off);
        }
        __syncthreads();

        // ---- S^T = K Q^T ----
        f32x4 st[4];
#pragma unroll
        for (int mt = 0; mt < 4; ++mt) st[mt] = (f32x4){0.f,0.f,0.f,0.f};
#pragma unroll
        for (int ks = 0; ks < 2; ++ks){
#pragma unroll
            for (int mt = 0; mt < 4; ++mt){
                short8 ak = *(const short8*)&Kl[16*mt + l15][32*ks + g*8];
                st[mt] = __builtin_amdgcn_mfma_f32_16x16x32_bf16(ak, qf[ks], st[mt], 0,0,0);
            }
        }

        // ---- online softmax for q-row l15 ----
        float pm = -1e30f;
#pragma unroll
        for (int mt = 0; mt < 4; ++mt)
#pragma unroll
            for (int r = 0; r < 4; ++r) pm = fmaxf(pm, st[mt][r]);
        pm = fmaxf(pm, __shfl_xor(pm, 16));
        pm = fmaxf(pm, __shfl_xor(pm, 32));
        float mnew = fmaxf(m_r, pm);
        float corr = __expf(m_r - mnew);
        float lsum = 0.f;
#pragma unroll
        for (int mt = 0; mt < 4; ++mt)
#pragma unroll
            for (int r = 0; r < 4; ++r){
                float p = __expf(st[mt][r] - mnew);
                st[mt][r] = p;
                lsum += p;
            }
        lsum += __shfl_xor(lsum, 16);
        lsum += __shfl_xor(lsum, 32);
        l_r = l_r * corr + lsum;
        m_r = mnew;

        // rescale O (rows q'=4g+r; corr lives at lane q')
        float cr[4];
#pragma unroll
        for (int r = 0; r < 4; ++r) cr[r] = __shfl(corr, 4 * g + r);
#pragma unroll
        for (int nt = 0; nt < 4; ++nt)
#pragma unroll
            for (int r = 0; r < 4; ++r) o[nt][r] *= cr[r];

        // ---- P -> LDS (bf16), per-wave buffer ----
#pragma unroll
        for (int mt = 0; mt < 4; ++mt){
            unsigned long long pp =
                  (unsigned long long)f2b(st[mt][0])
                | ((unsigned long long)f2b(st[mt][1]) << 16)
                | ((unsigned long long)f2b(st[mt][2]) << 32)
                | ((unsigned long long)f2b(st[mt][3]) << 48);
            *(unsigned long long*)&Pl[w][l15][16 * mt + 4 * g] = pp;
        }
        __syncthreads();                 // orders P writes before A-frag reads

        // ---- O += P V ----
#pragma unroll
        for (int ks = 0; ks < 2; ++ks){
            short8 ap = *(const short8*)&Pl[w][l15][32*ks + g*8];
#pragma unroll
            for (int nt = 0; nt < 4; ++nt){
                short8 bv2 = *(const short8*)&Vtl[16*nt + l15][32*ks + g*8];
                o[nt] = __builtin_amdgcn_mfma_f32_16x16x32_bf16(ap, bv2, o[nt], 0,0,0);
            }
        }
    }

    // ---- normalize + store fp32 out[b][s][h*64+e] ----
    float invl[4];
#pragma unroll
    for (int r = 0; r < 4; ++r) invl[r] = 1.f / __shfl(l_r, 4 * g + r);
    const int srow0 = qt * 64 + 16 * w + 4 * g;
#pragma unroll
    for (int nt = 0; nt < 4; ++nt)
#pragma unroll
        for (int r = 0; r < 4; ++r)
            out[((size_t)b * S_ + srow0 + r) * D_ + h * DH_ + 16 * nt + l15] =
                o[nt][r] * invl[r];
}

extern "C" void kernel_launch(void* const* d_in, const int* in_sizes, int n_in,
                              void* d_out, int out_size, void* d_ws, size_t ws_size,
                              hipStream_t stream) {
    const float* x  = (const float*)d_in[0];
    const float* Wq = (const float*)d_in[1];
    const float* bq = (const float*)d_in[2];
    const float* Wk = (const float*)d_in[3];
    const float* bk = (const float*)d_in[4];
    const float* Wv = (const float*)d_in[5];
    const float* bv = (const float*)d_in[6];
    float* out = (float*)d_out;

    // workspace layout (bytes): xb 16.78M | wt 6.29M | qb 16.78M | kb 16.78M | vt 16.78M
    char* wsp = (char*)d_ws;
    unsigned short* xb  = (unsigned short*)(wsp);
    unsigned short* wtg = (unsigned short*)(wsp + 16777216);
    unsigned short* qb  = (unsigned short*)(wsp + 23068672);
    unsigned short* kb  = (unsigned short*)(wsp + 39845888);
    unsigned short* vt  = (unsigned short*)(wsp + 56623104);

    cvt_x_kernel<<<4096, 256, 0, stream>>>(x, xb);
    cvt_w_kernel<<<3072, 256, 0, stream>>>(Wq, Wk, Wv, wtg);
    qkv_proj_mfma<<<dim3(64, 16), 256, 0, stream>>>(xb, wtg, bq, bk, bv, qb, kb, vt);
    attn_mfma<<<dim3(32, 64), 256, 0, stream>>>(qb, kb, vt, out);
}